// Round 17
// baseline (160.360 us; speedup 1.0000x reference)
//
#include <hip/hip_runtime.h>

typedef __attribute__((ext_vector_type(8))) short short8;
typedef __attribute__((ext_vector_type(4))) float f32x4;

typedef __attribute__((address_space(1))) const unsigned gas_u32;
typedef __attribute__((address_space(3))) unsigned las_u32;

static __device__ __forceinline__ void g2l16(const void* g, void* l) {
  __builtin_amdgcn_global_load_lds((gas_u32*)g, (las_u32*)l, 16, 0, 0);
}

static __device__ __forceinline__ short f2bf(float f) {
  union { float f; unsigned u; } v; v.f = f;
  unsigned r = (v.u + 0x7FFFu + ((v.u >> 16) & 1u)) >> 16;   // RNE
  return (short)r;
}

#define MF(a_, b_, c_) __builtin_amdgcn_mfma_f32_16x16x32_bf16(a_, b_, c_, 0, 0, 0)

// ---- elementwise bf16(k*m*s), 8 elems/thread at flat-index i ----
static __device__ __forceinline__ void maskmul8(const float* __restrict__ k,
                                                const float* __restrict__ m,
                                                float s, short* __restrict__ o8, int i) {
  const f32x4* kk = (const f32x4*)k + (size_t)i * 2;
  const f32x4* mm = (const f32x4*)m + (size_t)i * 2;
  f32x4 a0 = kk[0], a1 = kk[1], b0 = mm[0], b1 = mm[1];
  short8 o;
  o[0] = f2bf(a0[0] * b0[0] * s); o[1] = f2bf(a0[1] * b0[1] * s);
  o[2] = f2bf(a0[2] * b0[2] * s); o[3] = f2bf(a0[3] * b0[3] * s);
  o[4] = f2bf(a1[0] * b1[0] * s); o[5] = f2bf(a1[1] * b1[1] * s);
  o[6] = f2bf(a1[2] * b1[2] * s); o[7] = f2bf(a1[3] * b1[3] * s);
  ((short8*)o8)[i] = o;
}

// ---- x fp32 -> bf16 into zero-padded xbp[32][34][34][128], 8 elems/thread ----
static __device__ __forceinline__ void xcvt_body(const float* __restrict__ x,
                                                 short* __restrict__ xbp, int i) {
  int c8 = i & 15;
  int t = i >> 4;
  int wp = t % 34, t2 = t / 34;
  int hp = t2 % 34, b = t2 / 34;
  short8 o = {};
  if (hp >= 1 && hp <= 32 && wp >= 1 && wp <= 32) {
    const f32x4* s = (const f32x4*)(x + (((size_t)((b << 5) + hp - 1) << 5) + (wp - 1)) * 128 + c8 * 8);
    f32x4 a = s[0], bb2 = s[1];
    o[0] = f2bf(a[0]); o[1] = f2bf(a[1]); o[2] = f2bf(a[2]); o[3] = f2bf(a[3]);
    o[4] = f2bf(bb2[0]); o[5] = f2bf(bb2[1]); o[6] = f2bf(bb2[2]); o[7] = f2bf(bb2[3]);
  }
  ((short8*)xbp)[i] = o;
}

// ---- 64x64 GEMM tile, BK=128 double-buffered: C[M][N] = A[M][K] @ BT[N][K]^T ----
static __device__ __forceinline__ void gemm_tile(const short* __restrict__ A,
                                                 const short* __restrict__ BT,
                                                 short* __restrict__ C,
                                                 int M, int N, int K, int tile,
                                                 char* smem, int tid) {
  short (*As)[64][128] = (short(*)[64][128])smem;            // 2 x 16 KiB
  short (*Bs)[64][128] = (short(*)[64][128])(smem + 32768);  // 2 x 16 KiB
  const int ntiles = N >> 6;
  const int m0 = (tile / ntiles) << 6, n0 = (tile % ntiles) << 6;
  const int lane = tid & 63, wv = tid >> 6;
  const int wr = (wv >> 1) * 32, wc = (wv & 1) * 32;
  const int lr = lane & 15, lh = lane >> 4;

  const int rr = tid >> 4, sl = tid & 15;
  const int swz = sl ^ (rr & 7);
  const unsigned aOff = (unsigned)(m0 + rr) * K + swz * 8;
  const unsigned bOff = (unsigned)(n0 + rr) * K + swz * 8;
  const int ldsRow = 4 * wv;

  f32x4 acc[2][2] = {};

#define GSTm(buf_, kt_) do { \
    _Pragma("unroll") for (int j = 0; j < 4; ++j) \
      g2l16(A + aOff + (unsigned)j * 16u * (unsigned)K + (unsigned)(kt_) * 128u, \
            &As[buf_][j * 16 + ldsRow][0]); \
    _Pragma("unroll") for (int j = 0; j < 4; ++j) \
      g2l16(BT + bOff + (unsigned)j * 16u * (unsigned)K + (unsigned)(kt_) * 128u, \
            &Bs[buf_][j * 16 + ldsRow][0]); \
  } while (0)

  const int nk = K >> 7;
  GSTm(0, 0);
  asm volatile("s_waitcnt vmcnt(0)" ::: "memory");
  __syncthreads();

  for (int kt = 0; kt < nk; ++kt) {
    const int cur = kt & 1;
    if (kt + 1 < nk) { if (cur) GSTm(0, kt + 1); else GSTm(1, kt + 1); }
#pragma unroll
    for (int ks = 0; ks < 4; ++ks) {
      short8 af[2], bf[2];
#pragma unroll
      for (int i = 0; i < 2; ++i)
        af[i] = *(const short8*)&As[cur][wr + i * 16 + lr][((ks * 4 + lh) ^ (lr & 7)) * 8];
#pragma unroll
      for (int i = 0; i < 2; ++i)
        bf[i] = *(const short8*)&Bs[cur][wc + i * 16 + lr][((ks * 4 + lh) ^ (lr & 7)) * 8];
#pragma unroll
      for (int mi = 0; mi < 2; ++mi)
#pragma unroll
        for (int ni = 0; ni < 2; ++ni)
          acc[mi][ni] = MF(af[mi], bf[ni], acc[mi][ni]);
    }
    if (kt + 1 < nk) asm volatile("s_waitcnt vmcnt(0)" ::: "memory");
    __syncthreads();
  }
#pragma unroll
  for (int mi = 0; mi < 2; ++mi) {
    const int row = m0 + wr + mi * 16 + lh * 4;
#pragma unroll
    for (int ni = 0; ni < 2; ++ni) {
      const int col = n0 + wc + ni * 16 + lr;
#pragma unroll
      for (int q = 0; q < 4; ++q)
        C[(size_t)(row + q) * N + col] = f2bf(acc[mi][ni][q]);
    }
  }
#undef GSTm
}

// ---- device-scope global barrier (256 blocks, 256 threads; thread t spins on flags[t]) ----
static __device__ __forceinline__ void gbar(unsigned* flags, unsigned tag, int bid, int tid) {
  __syncthreads();
  if (tid == 0) {
    __threadfence();
    __hip_atomic_store(&flags[bid], tag, __ATOMIC_RELEASE, __HIP_MEMORY_SCOPE_AGENT);
  }
  while (__hip_atomic_load(&flags[tid], __ATOMIC_ACQUIRE, __HIP_MEMORY_SCOPE_AGENT) != tag)
    __builtin_amdgcn_s_sleep(1);
  __threadfence();
  __syncthreads();
}

// ======== mega weight-chain kernel: prep -> gemmB1 -> gemmEff in ONE launch ========
__global__ __launch_bounds__(256) void k_mega(const float* __restrict__ k0f,
                                              const float* __restrict__ m0f,
                                              const float* __restrict__ scf,
                                              const float* __restrict__ k1f,
                                              const float* __restrict__ m1f,
                                              const float* __restrict__ k2f,
                                              const float* __restrict__ m2f,
                                              const float* __restrict__ x,
                                              short* __restrict__ xbp,
                                              short* __restrict__ w1b,
                                              short* __restrict__ w2b,
                                              short* __restrict__ w3T,
                                              short* __restrict__ B1T,
                                              short* __restrict__ wET,
                                              unsigned* __restrict__ flags) {
  __shared__ __align__(16) char smem[65536];
  const int bid = blockIdx.x, tid = threadIdx.x;
  const unsigned E = __hip_atomic_load(&flags[256], __ATOMIC_RELAXED, __HIP_MEMORY_SCOPE_AGENT);

  // ---- phase A: 8 aux units/block ----
  // unit u: [0,288) w2b=bf16(k1*m1) | [288,544) w3T tile | [544,2048) xcvt 0..1503
  float (*tile)[33] = (float(*)[33])smem;
#pragma unroll 1
  for (int j = 0; j < 8; ++j) {
    const int u = j * 256 + bid;
    if (u < 288) {
      maskmul8(k1f, m1f, 1.0f, w2b, u * 256 + tid);
    } else if (u < 544) {
      const int idx = u - 288;
      int f0 = (idx & 15) * 32, d0 = (idx >> 4) * 32;
      int tx = tid & 31, ty = tid >> 5;
      __syncthreads();
#pragma unroll
      for (int i = 0; i < 4; ++i) {
        int d = d0 + ty + i * 8;
        size_t ix = (size_t)d * 512 + f0 + tx;
        tile[ty + i * 8][tx] = k2f[ix] * m2f[ix];
      }
      __syncthreads();
#pragma unroll
      for (int i = 0; i < 4; ++i) {
        int f = f0 + ty + i * 8;
        w3T[(size_t)f * 512 + d0 + tx] = f2bf(tile[tx][ty + i * 8]);
      }
    } else {
      xcvt_body(x, xbp, (u - 544) * 256 + tid);
    }
  }
  gbar(flags, E + 1, bid, tid);

  // ---- phase B: gemmB1 on blocks 0..143; aux on 144..255 ----
  // B1T[512][1152] = w3T[512][512] @ w2b[1152][512]^T
  if (bid < 144) {
    gemm_tile(w3T, w2b, B1T, 512, 1152, 512, bid, smem, tid);
  } else {
    const int ab = bid - 144;   // 0..111
#pragma unroll 1
    for (int j = 0; j < 9; ++j) {
      const int s = ab * 9 + j;  // 0..1007
      if (s < 648) maskmul8(k0f, m0f, scf[0], w1b, s * 256 + tid);
      else xcvt_body(x, xbp, (1504 + s - 648) * 256 + tid);   // xcvt 1504..1863
    }
  }
  gbar(flags, E + 2, bid, tid);

  // ---- phase C: gemmEff on blocks 0..143; aux on 144..255 ----
  // wET[512][1152] = B1T[512][1152] @ w1b[1152][1152]^T
  if (bid < 144) {
    gemm_tile(B1T, w1b, wET, 512, 1152, 1152, bid, smem, tid);
  } else {
    const int ab = bid - 144;
#pragma unroll 1
    for (int j = 0; j < 4; ++j)
      xcvt_body(x, xbp, (1864 + ab * 4 + j) * 256 + tid);     // xcvt 1864..2311
  }

  if (bid == 0 && tid == 0)
    __hip_atomic_store(&flags[256], E + 2, __ATOMIC_RELAXED, __HIP_MEMORY_SCOPE_AGENT);
}

// ======== conv: 256x128 tile, 4 waves x (128x64), single-buffer BK=64, 1 barrier/phase ========
// (R10/R16-proven structure, unchanged)
#define RD_A(mf_, ks_) \
  (*(const short8*)&As[wr * 128 + (mf_) * 16 + lr][(((ks_) * 4 + lh) ^ (lr & 7)) * 8])
#define RD_B(nf_, ks_) \
  (*(const short8*)&Bs[wc * 64 + (nf_) * 16 + lr][(((ks_) * 4 + lh) ^ (lr & 7)) * 8])

#define STAGE_AQ(q_, tt_) do { \
  const int tc_ = (tt_) > 17 ? 17 : (tt_); \
  const int khw_ = tc_ >> 1; const int kh_ = (khw_ * 11) >> 5; const int kw_ = khw_ - kh_ * 3; \
  const int ao_ = (kh_ * 34 + kw_) * 128 + ((tc_ & 1) << 6) + (q_) * 4352; \
  g2l16(xbp + aBase + ao_, &As[(q_) * 32 + ldsA][0]); \
  g2l16(xbp + aBase + 17408 + ao_, &As[128 + (q_) * 32 + ldsA][0]); } while (0)

#define STAGE_B(tt_) do { \
  const int tc_ = (tt_) > 17 ? 17 : (tt_); \
  g2l16(wT + bBase +          tc_ * 64, &Bs[     ldsA][0]); \
  g2l16(wT + bBase +  36864 + tc_ * 64, &Bs[32 + ldsA][0]); \
  g2l16(wT + bBase +  73728 + tc_ * 64, &Bs[64 + ldsA][0]); \
  g2l16(wT + bBase + 110592 + tc_ * 64, &Bs[96 + ldsA][0]); } while (0)

#define MFMA16(p_) \
  acc[2*(p_)  ][0] = MF(a0k0, bfr[0][0], acc[2*(p_)  ][0]); \
  acc[2*(p_)  ][1] = MF(a0k0, bfr[1][0], acc[2*(p_)  ][1]); \
  acc[2*(p_)  ][2] = MF(a0k0, bfr[2][0], acc[2*(p_)  ][2]); \
  acc[2*(p_)  ][3] = MF(a0k0, bfr[3][0], acc[2*(p_)  ][3]); \
  acc[2*(p_)+1][0] = MF(a1k0, bfr[0][0], acc[2*(p_)+1][0]); \
  acc[2*(p_)+1][1] = MF(a1k0, bfr[1][0], acc[2*(p_)+1][1]); \
  acc[2*(p_)+1][2] = MF(a1k0, bfr[2][0], acc[2*(p_)+1][2]); \
  acc[2*(p_)+1][3] = MF(a1k0, bfr[3][0], acc[2*(p_)+1][3]); \
  acc[2*(p_)  ][0] = MF(a0k1, bfr[0][1], acc[2*(p_)  ][0]); \
  acc[2*(p_)  ][1] = MF(a0k1, bfr[1][1], acc[2*(p_)  ][1]); \
  acc[2*(p_)  ][2] = MF(a0k1, bfr[2][1], acc[2*(p_)  ][2]); \
  acc[2*(p_)  ][3] = MF(a0k1, bfr[3][1], acc[2*(p_)  ][3]); \
  acc[2*(p_)+1][0] = MF(a1k1, bfr[0][1], acc[2*(p_)+1][0]); \
  acc[2*(p_)+1][1] = MF(a1k1, bfr[1][1], acc[2*(p_)+1][1]); \
  acc[2*(p_)+1][2] = MF(a1k1, bfr[2][1], acc[2*(p_)+1][2]); \
  acc[2*(p_)+1][3] = MF(a1k1, bfr[3][1], acc[2*(p_)+1][3]);

#define PHASE(p_, PRE, WAITV, ...) do { \
  PRE; \
  short8 a0k0 = RD_A(2*(p_), 0),   a0k1 = RD_A(2*(p_), 1); \
  short8 a1k0 = RD_A(2*(p_)+1, 0), a1k1 = RD_A(2*(p_)+1, 1); \
  __VA_ARGS__ \
  asm volatile("s_waitcnt lgkmcnt(0)" ::: "memory"); \
  __builtin_amdgcn_sched_barrier(0); \
  __builtin_amdgcn_s_setprio(1); \
  MFMA16(p_) \
  __builtin_amdgcn_s_setprio(0); \
  WAITV; \
  __builtin_amdgcn_s_barrier(); \
} while (0)

#define LOADB do { \
  bfr[0][0] = RD_B(0, 0); bfr[0][1] = RD_B(0, 1); \
  bfr[1][0] = RD_B(1, 0); bfr[1][1] = RD_B(1, 1); \
  bfr[2][0] = RD_B(2, 0); bfr[2][1] = RD_B(2, 1); \
  bfr[3][0] = RD_B(3, 0); bfr[3][1] = RD_B(3, 1); } while (0)

#define VM4 asm volatile("s_waitcnt vmcnt(4)" ::: "memory")
#define VM6 asm volatile("s_waitcnt vmcnt(6)" ::: "memory")
#define VM8 asm volatile("s_waitcnt vmcnt(8)" ::: "memory")

__global__ __launch_bounds__(256, 2) void k_conv(const short* __restrict__ xbp,
                                                 const short* __restrict__ wT,
                                                 const float* __restrict__ bias,
                                                 float* __restrict__ outp) {
  __shared__ __align__(16) short As[256][64];   // 32 KiB
  __shared__ __align__(16) short Bs[128][64];   // 16 KiB
  int bid = blockIdx.x;
  bid = (bid & 7) * 64 + (bid >> 3);            // bijective XCD swizzle (512 % 8 == 0)
  const int mt = bid >> 2, nt = bid & 3;
  const int m0 = mt << 8, n0 = nt << 7;
  const int tid = threadIdx.x;
  const int lane = tid & 63, wid = tid >> 6;    // 4 waves: 2M x 2N
  const int wr = wid >> 1, wc = wid & 1;
  const int lr = lane & 15, lh = lane >> 4;

  f32x4 acc[8][4] = {};
  short8 bfr[4][2];

  const int rsub = tid >> 3;                    // 0..31
  const int sw = (tid & 7) ^ (rsub & 7);        // pre-swizzled 16B slot
  const int ldsA = wid * 8;                     // wave-uniform LDS row base

  const int Mb = m0 + rsub;
  const int b = Mb >> 10, h0 = (Mb >> 5) & 31, w = Mb & 31;
  const unsigned aBase = (unsigned)((b * 34 + h0) * 34 + w) * 128 + sw * 8;
  const unsigned bBase = (unsigned)(n0 + rsub) * 1152 + sw * 8;

  STAGE_B(0);
  STAGE_AQ(0, 0); STAGE_AQ(1, 0); STAGE_AQ(2, 0);
  asm volatile("s_waitcnt vmcnt(0)" ::: "memory");
  __builtin_amdgcn_s_barrier();

  for (int t = 0; t < 18; ++t) {
    const int tn = t + 1;  // clamped inside STAGE macros (idempotent restage at tail)
    PHASE(0, LOADB, VM4, STAGE_AQ(3, t););
    PHASE(1, ,      VM6, STAGE_B(tn););
    PHASE(2, ,      VM8, STAGE_AQ(0, tn); STAGE_AQ(1, tn););
    PHASE(3, ,      VM4, STAGE_AQ(2, tn););
  }
  asm volatile("s_waitcnt vmcnt(0)" ::: "memory");

  // epilogue: fp32 + bias
  const int orow = m0 + wr * 128, ocol = n0 + wc * 64;
#pragma unroll
  for (int mf = 0; mf < 8; ++mf) {
    const int row = orow + mf * 16 + lh * 4;
#pragma unroll
    for (int nf = 0; nf < 4; ++nf) {
      const int col = ocol + nf * 16 + lr;
      const float bv = bias[col];
#pragma unroll
      for (int q = 0; q < 4; ++q)
        outp[(size_t)(row + q) * 512 + col] = acc[mf][nf][q] + bv;
    }
  }
}

extern "C" void kernel_launch(void* const* d_in, const int* in_sizes, int n_in,
                              void* d_out, int out_size, void* d_ws, size_t ws_size,
                              hipStream_t stream) {
  (void)in_sizes; (void)n_in; (void)out_size; (void)ws_size;
  const float* x    = (const float*)d_in[0];
  const float* k0   = (const float*)d_in[1];
  const float* k1   = (const float*)d_in[2];
  const float* k2   = (const float*)d_in[3];
  const float* m0   = (const float*)d_in[4];
  const float* m1   = (const float*)d_in[5];
  const float* m2   = (const float*)d_in[6];
  const float* sc   = (const float*)d_in[7];
  const float* bias = (const float*)d_in[8];
  float* outp = (float*)d_out;
  char* ws = (char*)d_ws;

  short* xbp   = (short*)(ws);              // 32*34*34*128 bf16 = 9,469,952 B
  short* w1b   = (short*)(ws + 9469952);    // 1152*1152 bf16    = 2,654,208 B
  short* w2b   = (short*)(ws + 12124160);   // 1152*512 bf16     = 1,179,648 B (plain)
  short* w3T   = (short*)(ws + 13303808);   // 512*512 bf16      =   524,288 B
  short* B1T   = (short*)(ws + 13828096);   // 512*1152 bf16     = 1,179,648 B
  short* wET   = (short*)(ws + 15007744);   // 512*1152 bf16     = 1,179,648 B
  unsigned* fl = (unsigned*)(ws + 16187392);// 257 u32 barrier flags + epoch

  k_mega<<<256, 256, 0, stream>>>(k0, m0, sc, k1, m1, k2, m2, x, xbp,
                                  w1b, w2b, w3T, B1T, wET, fl);
  k_conv<<<512, 256, 0, stream>>>(xbp, wET, bias, outp);
}

// Round 18
// 75.576 us; speedup vs baseline: 2.1218x; 2.1218x over previous
//
#include <hip/hip_runtime.h>

typedef __attribute__((ext_vector_type(8))) short short8;
typedef __attribute__((ext_vector_type(4))) float f32x4;

typedef __attribute__((address_space(1))) const unsigned gas_u32;
typedef __attribute__((address_space(3))) unsigned las_u32;

static __device__ __forceinline__ void g2l16(const void* g, void* l) {
  __builtin_amdgcn_global_load_lds((gas_u32*)g, (las_u32*)l, 16, 0, 0);
}

static __device__ __forceinline__ short f2bf(float f) {
  union { float f; unsigned u; } v; v.f = f;
  unsigned r = (v.u + 0x7FFFu + ((v.u >> 16) & 1u)) >> 16;   // RNE
  return (short)r;
}

#define MF(a_, b_, c_) __builtin_amdgcn_mfma_f32_16x16x32_bf16(a_, b_, c_, 0, 0, 0)

// ---- elementwise bf16(k*m*s), 8 elems/thread at flat-index i ----
static __device__ __forceinline__ void maskmul8(const float* __restrict__ k,
                                                const float* __restrict__ m,
                                                float s, short* __restrict__ o8, int i) {
  const f32x4* kk = (const f32x4*)k + (size_t)i * 2;
  const f32x4* mm = (const f32x4*)m + (size_t)i * 2;
  f32x4 a0 = kk[0], a1 = kk[1], b0 = mm[0], b1 = mm[1];
  short8 o;
  o[0] = f2bf(a0[0] * b0[0] * s); o[1] = f2bf(a0[1] * b0[1] * s);
  o[2] = f2bf(a0[2] * b0[2] * s); o[3] = f2bf(a0[3] * b0[3] * s);
  o[4] = f2bf(a1[0] * b1[0] * s); o[5] = f2bf(a1[1] * b1[1] * s);
  o[6] = f2bf(a1[2] * b1[2] * s); o[7] = f2bf(a1[3] * b1[3] * s);
  ((short8*)o8)[i] = o;
}

// ---- x fp32 -> bf16 into zero-padded xbp[32][34][34][128], 8 elems/thread ----
static __device__ __forceinline__ void xcvt_body(const float* __restrict__ x,
                                                 short* __restrict__ xbp, int i) {
  int c8 = i & 15;
  int t = i >> 4;
  int wp = t % 34, t2 = t / 34;
  int hp = t2 % 34, b = t2 / 34;
  short8 o = {};
  if (hp >= 1 && hp <= 32 && wp >= 1 && wp <= 32) {
    const f32x4* s = (const f32x4*)(x + (((size_t)((b << 5) + hp - 1) << 5) + (wp - 1)) * 128 + c8 * 8);
    f32x4 a = s[0], bb2 = s[1];
    o[0] = f2bf(a[0]); o[1] = f2bf(a[1]); o[2] = f2bf(a[2]); o[3] = f2bf(a[3]);
    o[4] = f2bf(bb2[0]); o[5] = f2bf(bb2[1]); o[6] = f2bf(bb2[2]); o[7] = f2bf(bb2[3]);
  }
  ((short8*)xbp)[i] = o;
}

// ---- prep1: w2b = bf16(k1*m1) plain | w3T = tmask(k2,m2) | xcvt blocks 0..1023 ----
__global__ __launch_bounds__(256) void k_prep1(const float* __restrict__ k1f,
                                               const float* __restrict__ m1f,
                                               const float* __restrict__ k2f,
                                               const float* __restrict__ m2f,
                                               short* __restrict__ w2b,
                                               short* __restrict__ w3T,
                                               const float* __restrict__ x,
                                               short* __restrict__ xbp) {
  __shared__ float tile[32][33];
  const int bb = blockIdx.x, tid = threadIdx.x;
  if (bb < 288) {
    maskmul8(k1f, m1f, 1.0f, w2b, bb * 256 + tid);            // 1152x512 plain
  } else if (bb < 544) {
    const int idx = bb - 288;                                 // w3T: 512x512 masked transpose
    int f0 = (idx & 15) * 32, d0 = (idx >> 4) * 32;
    int tx = tid & 31, ty = tid >> 5;
#pragma unroll
    for (int i = 0; i < 4; ++i) {
      int d = d0 + ty + i * 8;
      size_t ix = (size_t)d * 512 + f0 + tx;
      tile[ty + i * 8][tx] = k2f[ix] * m2f[ix];
    }
    __syncthreads();
#pragma unroll
    for (int i = 0; i < 4; ++i) {
      int f = f0 + ty + i * 8;
      w3T[(size_t)f * 512 + d0 + tx] = f2bf(tile[tx][ty + i * 8]);
    }
  } else {
    xcvt_body(x, xbp, (bb - 544) * 256 + tid);                // xcvt blocks 0..1023
  }
}

// ---- bf16 GEMM 64x64 tiles, BK=128 double-buffered prefetch (blocks < 144),
//      merged tail work: maskmul (nmask blocks) then xcvt ----
// C[M][N] = A[M][K] @ BT[N][K]^T ; K % 128 == 0
__global__ __launch_bounds__(256) void k_gemmx(const short* __restrict__ A,
                                               const short* __restrict__ BT,
                                               short* __restrict__ C, int M, int N, int K,
                                               const float* __restrict__ x,
                                               short* __restrict__ xbp, int xoff,
                                               const float* __restrict__ mkf,
                                               const float* __restrict__ mmf,
                                               const float* __restrict__ mscf,
                                               short* __restrict__ mout, int nmask) {
  __shared__ __align__(16) short As[2][64][128];   // 32 KiB
  __shared__ __align__(16) short Bs[2][64][128];   // 32 KiB
  if (blockIdx.x >= 144) {
    const int r = (int)blockIdx.x - 144;
    if (r < nmask) maskmul8(mkf, mmf, mscf[0], mout, r * 256 + (int)threadIdx.x);
    else xcvt_body(x, xbp, (xoff + r - nmask) * 256 + (int)threadIdx.x);
    return;
  }
  const int ntiles = N >> 6;
  const int m0 = (blockIdx.x / ntiles) << 6, n0 = (blockIdx.x % ntiles) << 6;
  const int tid = threadIdx.x;
  const int lane = tid & 63, wv = tid >> 6;
  const int wr = (wv >> 1) * 32, wc = (wv & 1) * 32;
  const int lr = lane & 15, lh = lane >> 4;

  const int rr = tid >> 4, sl = tid & 15;
  const int swz = sl ^ (rr & 7);
  const unsigned aOff = (unsigned)(m0 + rr) * K + swz * 8;
  const unsigned bOff = (unsigned)(n0 + rr) * K + swz * 8;
  const int ldsRow = 4 * wv;

  f32x4 acc[2][2] = {};

#define GST(buf_, kt_) do { \
    _Pragma("unroll") for (int j = 0; j < 4; ++j) \
      g2l16(A + aOff + (unsigned)j * 16u * (unsigned)K + (unsigned)(kt_) * 128u, \
            &As[buf_][j * 16 + ldsRow][0]); \
    _Pragma("unroll") for (int j = 0; j < 4; ++j) \
      g2l16(BT + bOff + (unsigned)j * 16u * (unsigned)K + (unsigned)(kt_) * 128u, \
            &Bs[buf_][j * 16 + ldsRow][0]); \
  } while (0)

  const int nk = K >> 7;
  GST(0, 0);
  asm volatile("s_waitcnt vmcnt(0)" ::: "memory");
  __builtin_amdgcn_s_barrier();

  for (int kt = 0; kt < nk; ++kt) {
    const int cur = kt & 1;
    if (kt + 1 < nk) { if (cur) GST(0, kt + 1); else GST(1, kt + 1); }
#pragma unroll
    for (int ks = 0; ks < 4; ++ks) {
      short8 af[2], bf[2];
#pragma unroll
      for (int i = 0; i < 2; ++i)
        af[i] = *(const short8*)&As[cur][wr + i * 16 + lr][((ks * 4 + lh) ^ (lr & 7)) * 8];
#pragma unroll
      for (int i = 0; i < 2; ++i)
        bf[i] = *(const short8*)&Bs[cur][wc + i * 16 + lr][((ks * 4 + lh) ^ (lr & 7)) * 8];
#pragma unroll
      for (int mi = 0; mi < 2; ++mi)
#pragma unroll
        for (int ni = 0; ni < 2; ++ni)
          acc[mi][ni] = MF(af[mi], bf[ni], acc[mi][ni]);
    }
    if (kt + 1 < nk) asm volatile("s_waitcnt vmcnt(0)" ::: "memory");
    __builtin_amdgcn_s_barrier();
  }
#pragma unroll
  for (int mi = 0; mi < 2; ++mi) {
    const int row = m0 + wr + mi * 16 + lh * 4;
#pragma unroll
    for (int ni = 0; ni < 2; ++ni) {
      const int col = n0 + wc + ni * 16 + lr;
#pragma unroll
      for (int q = 0; q < 4; ++q)
        C[(size_t)(row + q) * N + col] = f2bf(acc[mi][ni][q]);
    }
  }
#undef GST
}

// ======== conv: 256x128 tile, 4 waves x (128x64), single-buffer BK=64, 1 barrier/phase ========
// (R10/R16-proven 43.5 us structure; output via nontemporal stores)
#define RD_A(mf_, ks_) \
  (*(const short8*)&As[wr * 128 + (mf_) * 16 + lr][(((ks_) * 4 + lh) ^ (lr & 7)) * 8])
#define RD_B(nf_, ks_) \
  (*(const short8*)&Bs[wc * 64 + (nf_) * 16 + lr][(((ks_) * 4 + lh) ^ (lr & 7)) * 8])

#define STAGE_AQ(q_, tt_) do { \
  const int tc_ = (tt_) > 17 ? 17 : (tt_); \
  const int khw_ = tc_ >> 1; const int kh_ = (khw_ * 11) >> 5; const int kw_ = khw_ - kh_ * 3; \
  const int ao_ = (kh_ * 34 + kw_) * 128 + ((tc_ & 1) << 6) + (q_) * 4352; \
  g2l16(xbp + aBase + ao_, &As[(q_) * 32 + ldsA][0]); \
  g2l16(xbp + aBase + 17408 + ao_, &As[128 + (q_) * 32 + ldsA][0]); } while (0)

#define STAGE_B(tt_) do { \
  const int tc_ = (tt_) > 17 ? 17 : (tt_); \
  g2l16(wT + bBase +          tc_ * 64, &Bs[     ldsA][0]); \
  g2l16(wT + bBase +  36864 + tc_ * 64, &Bs[32 + ldsA][0]); \
  g2l16(wT + bBase +  73728 + tc_ * 64, &Bs[64 + ldsA][0]); \
  g2l16(wT + bBase + 110592 + tc_ * 64, &Bs[96 + ldsA][0]); } while (0)

#define MFMA16(p_) \
  acc[2*(p_)  ][0] = MF(a0k0, bfr[0][0], acc[2*(p_)  ][0]); \
  acc[2*(p_)  ][1] = MF(a0k0, bfr[1][0], acc[2*(p_)  ][1]); \
  acc[2*(p_)  ][2] = MF(a0k0, bfr[2][0], acc[2*(p_)  ][2]); \
  acc[2*(p_)  ][3] = MF(a0k0, bfr[3][0], acc[2*(p_)  ][3]); \
  acc[2*(p_)+1][0] = MF(a1k0, bfr[0][0], acc[2*(p_)+1][0]); \
  acc[2*(p_)+1][1] = MF(a1k0, bfr[1][0], acc[2*(p_)+1][1]); \
  acc[2*(p_)+1][2] = MF(a1k0, bfr[2][0], acc[2*(p_)+1][2]); \
  acc[2*(p_)+1][3] = MF(a1k0, bfr[3][0], acc[2*(p_)+1][3]); \
  acc[2*(p_)  ][0] = MF(a0k1, bfr[0][1], acc[2*(p_)  ][0]); \
  acc[2*(p_)  ][1] = MF(a0k1, bfr[1][1], acc[2*(p_)  ][1]); \
  acc[2*(p_)  ][2] = MF(a0k1, bfr[2][1], acc[2*(p_)  ][2]); \
  acc[2*(p_)  ][3] = MF(a0k1, bfr[3][1], acc[2*(p_)  ][3]); \
  acc[2*(p_)+1][0] = MF(a1k1, bfr[0][1], acc[2*(p_)+1][0]); \
  acc[2*(p_)+1][1] = MF(a1k1, bfr[1][1], acc[2*(p_)+1][1]); \
  acc[2*(p_)+1][2] = MF(a1k1, bfr[2][1], acc[2*(p_)+1][2]); \
  acc[2*(p_)+1][3] = MF(a1k1, bfr[3][1], acc[2*(p_)+1][3]);

#define PHASE(p_, PRE, WAITV, ...) do { \
  PRE; \
  short8 a0k0 = RD_A(2*(p_), 0),   a0k1 = RD_A(2*(p_), 1); \
  short8 a1k0 = RD_A(2*(p_)+1, 0), a1k1 = RD_A(2*(p_)+1, 1); \
  __VA_ARGS__ \
  asm volatile("s_waitcnt lgkmcnt(0)" ::: "memory"); \
  __builtin_amdgcn_sched_barrier(0); \
  __builtin_amdgcn_s_setprio(1); \
  MFMA16(p_) \
  __builtin_amdgcn_s_setprio(0); \
  WAITV; \
  __builtin_amdgcn_s_barrier(); \
} while (0)

#define LOADB do { \
  bfr[0][0] = RD_B(0, 0); bfr[0][1] = RD_B(0, 1); \
  bfr[1][0] = RD_B(1, 0); bfr[1][1] = RD_B(1, 1); \
  bfr[2][0] = RD_B(2, 0); bfr[2][1] = RD_B(2, 1); \
  bfr[3][0] = RD_B(3, 0); bfr[3][1] = RD_B(3, 1); } while (0)

#define VM4 asm volatile("s_waitcnt vmcnt(4)" ::: "memory")
#define VM6 asm volatile("s_waitcnt vmcnt(6)" ::: "memory")
#define VM8 asm volatile("s_waitcnt vmcnt(8)" ::: "memory")

__global__ __launch_bounds__(256, 2) void k_conv(const short* __restrict__ xbp,
                                                 const short* __restrict__ wT,
                                                 const float* __restrict__ bias,
                                                 float* __restrict__ outp) {
  __shared__ __align__(16) short As[256][64];   // 32 KiB
  __shared__ __align__(16) short Bs[128][64];   // 16 KiB
  int bid = blockIdx.x;
  bid = (bid & 7) * 64 + (bid >> 3);            // bijective XCD swizzle (512 % 8 == 0)
  const int mt = bid >> 2, nt = bid & 3;
  const int m0 = mt << 8, n0 = nt << 7;
  const int tid = threadIdx.x;
  const int lane = tid & 63, wid = tid >> 6;    // 4 waves: 2M x 2N
  const int wr = wid >> 1, wc = wid & 1;
  const int lr = lane & 15, lh = lane >> 4;

  f32x4 acc[8][4] = {};
  short8 bfr[4][2];

  const int rsub = tid >> 3;                    // 0..31
  const int sw = (tid & 7) ^ (rsub & 7);        // pre-swizzled 16B slot
  const int ldsA = wid * 8;                     // wave-uniform LDS row base

  const int Mb = m0 + rsub;
  const int b = Mb >> 10, h0 = (Mb >> 5) & 31, w = Mb & 31;
  const unsigned aBase = (unsigned)((b * 34 + h0) * 34 + w) * 128 + sw * 8;
  const unsigned bBase = (unsigned)(n0 + rsub) * 1152 + sw * 8;

  STAGE_B(0);
  STAGE_AQ(0, 0); STAGE_AQ(1, 0); STAGE_AQ(2, 0);
  asm volatile("s_waitcnt vmcnt(0)" ::: "memory");
  __builtin_amdgcn_s_barrier();

  for (int t = 0; t < 18; ++t) {
    const int tn = t + 1;  // clamped inside STAGE macros (idempotent restage at tail)
    PHASE(0, LOADB, VM4, STAGE_AQ(3, t););
    PHASE(1, ,      VM6, STAGE_B(tn););
    PHASE(2, ,      VM8, STAGE_AQ(0, tn); STAGE_AQ(1, tn););
    PHASE(3, ,      VM4, STAGE_AQ(2, tn););
  }
  asm volatile("s_waitcnt vmcnt(0)" ::: "memory");

  // epilogue: fp32 + bias, nontemporal (output never re-read; keep L2 for inputs)
  const int orow = m0 + wr * 128, ocol = n0 + wc * 64;
#pragma unroll
  for (int mf = 0; mf < 8; ++mf) {
    const int row = orow + mf * 16 + lh * 4;
#pragma unroll
    for (int nf = 0; nf < 4; ++nf) {
      const int col = ocol + nf * 16 + lr;
      const float bv = bias[col];
#pragma unroll
      for (int q = 0; q < 4; ++q)
        __builtin_nontemporal_store(acc[mf][nf][q] + bv,
                                    &outp[(size_t)(row + q) * 512 + col]);
    }
  }
}

extern "C" void kernel_launch(void* const* d_in, const int* in_sizes, int n_in,
                              void* d_out, int out_size, void* d_ws, size_t ws_size,
                              hipStream_t stream) {
  (void)in_sizes; (void)n_in; (void)out_size; (void)ws_size;
  const float* x    = (const float*)d_in[0];
  const float* k0   = (const float*)d_in[1];
  const float* k1   = (const float*)d_in[2];
  const float* k2   = (const float*)d_in[3];
  const float* m0   = (const float*)d_in[4];
  const float* m1   = (const float*)d_in[5];
  const float* m2   = (const float*)d_in[6];
  const float* sc   = (const float*)d_in[7];
  const float* bias = (const float*)d_in[8];
  float* outp = (float*)d_out;
  char* ws = (char*)d_ws;

  short* xbp = (short*)(ws);              // 32*34*34*128 bf16 = 9,469,952 B
  short* w1b = (short*)(ws + 9469952);    // 1152*1152 bf16    = 2,654,208 B
  short* w2b = (short*)(ws + 12124160);   // 1152*512 bf16     = 1,179,648 B (plain)
  short* w3T = (short*)(ws + 13303808);   // 512*512 bf16      =   524,288 B
  short* B1T = (short*)(ws + 13828096);   // 512*1152 bf16     = 1,179,648 B
  short* wET = (short*)(ws + 15007744);   // 512*1152 bf16     = 1,179,648 B

  // pipeline: prep1{w2b,w3T,xcvt[0..1023]} -> gemmB1 || w1b-maskmul || xcvt[1024..1535]
  //           -> gemmEff || xcvt[1536..2311] -> conv
  k_prep1<<<1568, 256, 0, stream>>>(k1, m1, k2, m2, w2b, w3T, x, xbp);
  // B1T[512][1152] = w3T[512][512] @ w2b[1152][512]^T  (K=512, 4 BK-stages)
  k_gemmx<<<1304, 256, 0, stream>>>(w3T, w2b, B1T, 512, 1152, 512,
                                    x, xbp, 1024, k0, m0, sc, w1b, 648);
  // wET[512][1152] = B1T[512][1152] @ w1b[1152][1152]^T  (K=1152, 9 BK-stages)
  k_gemmx<<<920, 256, 0, stream>>>(B1T, w1b, wET, 512, 1152, 1152,
                                   x, xbp, 1536, (const float*)nullptr,
                                   (const float*)nullptr, (const float*)nullptr,
                                   (short*)nullptr, 0);
  k_conv<<<512, 256, 0, stream>>>(xbp, wET, bias, outp);
}

// Round 19
// 69.201 us; speedup vs baseline: 2.3173x; 1.0921x over previous
//
#include <hip/hip_runtime.h>

typedef __attribute__((ext_vector_type(8))) short short8;
typedef __attribute__((ext_vector_type(4))) float f32x4;

typedef __attribute__((address_space(1))) const unsigned gas_u32;
typedef __attribute__((address_space(3))) unsigned las_u32;

static __device__ __forceinline__ void g2l16(const void* g, void* l) {
  __builtin_amdgcn_global_load_lds((gas_u32*)g, (las_u32*)l, 16, 0, 0);
}

static __device__ __forceinline__ short f2bf(float f) {
  union { float f; unsigned u; } v; v.f = f;
  unsigned r = (v.u + 0x7FFFu + ((v.u >> 16) & 1u)) >> 16;   // RNE
  return (short)r;
}

#define MF(a_, b_, c_) __builtin_amdgcn_mfma_f32_16x16x32_bf16(a_, b_, c_, 0, 0, 0)

// ---- elementwise bf16(k*m*s), 8 elems/thread at flat-index i ----
static __device__ __forceinline__ void maskmul8(const float* __restrict__ k,
                                                const float* __restrict__ m,
                                                float s, short* __restrict__ o8, int i) {
  const f32x4* kk = (const f32x4*)k + (size_t)i * 2;
  const f32x4* mm = (const f32x4*)m + (size_t)i * 2;
  f32x4 a0 = kk[0], a1 = kk[1], b0 = mm[0], b1 = mm[1];
  short8 o;
  o[0] = f2bf(a0[0] * b0[0] * s); o[1] = f2bf(a0[1] * b0[1] * s);
  o[2] = f2bf(a0[2] * b0[2] * s); o[3] = f2bf(a0[3] * b0[3] * s);
  o[4] = f2bf(a1[0] * b1[0] * s); o[5] = f2bf(a1[1] * b1[1] * s);
  o[6] = f2bf(a1[2] * b1[2] * s); o[7] = f2bf(a1[3] * b1[3] * s);
  ((short8*)o8)[i] = o;
}

// ---- x fp32 -> bf16 into zero-padded xbp[32][34][34][128], 8 elems/thread ----
static __device__ __forceinline__ void xcvt_body(const float* __restrict__ x,
                                                 short* __restrict__ xbp, int i) {
  int c8 = i & 15;
  int t = i >> 4;
  int wp = t % 34, t2 = t / 34;
  int hp = t2 % 34, b = t2 / 34;
  short8 o = {};
  if (hp >= 1 && hp <= 32 && wp >= 1 && wp <= 32) {
    const f32x4* s = (const f32x4*)(x + (((size_t)((b << 5) + hp - 1) << 5) + (wp - 1)) * 128 + c8 * 8);
    f32x4 a = s[0], bb2 = s[1];
    o[0] = f2bf(a[0]); o[1] = f2bf(a[1]); o[2] = f2bf(a[2]); o[3] = f2bf(a[3]);
    o[4] = f2bf(bb2[0]); o[5] = f2bf(bb2[1]); o[6] = f2bf(bb2[2]); o[7] = f2bf(bb2[3]);
  }
  ((short8*)xbp)[i] = o;
}

// ---- prep1: w2b = bf16(k1*m1) plain | w3T = tmask(k2,m2) | xcvt blocks 0..1023 ----
__global__ __launch_bounds__(256) void k_prep1(const float* __restrict__ k1f,
                                               const float* __restrict__ m1f,
                                               const float* __restrict__ k2f,
                                               const float* __restrict__ m2f,
                                               short* __restrict__ w2b,
                                               short* __restrict__ w3T,
                                               const float* __restrict__ x,
                                               short* __restrict__ xbp) {
  __shared__ float tile[32][33];
  const int bb = blockIdx.x, tid = threadIdx.x;
  if (bb < 288) {
    maskmul8(k1f, m1f, 1.0f, w2b, bb * 256 + tid);            // 1152x512 plain
  } else if (bb < 544) {
    const int idx = bb - 288;                                 // w3T: 512x512 masked transpose
    int f0 = (idx & 15) * 32, d0 = (idx >> 4) * 32;
    int tx = tid & 31, ty = tid >> 5;
#pragma unroll
    for (int i = 0; i < 4; ++i) {
      int d = d0 + ty + i * 8;
      size_t ix = (size_t)d * 512 + f0 + tx;
      tile[ty + i * 8][tx] = k2f[ix] * m2f[ix];
    }
    __syncthreads();
#pragma unroll
    for (int i = 0; i < 4; ++i) {
      int f = f0 + ty + i * 8;
      w3T[(size_t)f * 512 + d0 + tx] = f2bf(tile[tx][ty + i * 8]);
    }
  } else {
    xcvt_body(x, xbp, (bb - 544) * 256 + tid);                // xcvt blocks 0..1023
  }
}

// ---- bf16 GEMM 64x64 tiles, BK=128 double-buffered prefetch (blocks < 144),
//      merged tail work: maskmul (nmask blocks) then xcvt ----
// C[M][N] = A[M][K] @ BT[N][K]^T ; K % 128 == 0
__global__ __launch_bounds__(256) void k_gemmx(const short* __restrict__ A,
                                               const short* __restrict__ BT,
                                               short* __restrict__ C, int M, int N, int K,
                                               const float* __restrict__ x,
                                               short* __restrict__ xbp, int xoff,
                                               const float* __restrict__ mkf,
                                               const float* __restrict__ mmf,
                                               const float* __restrict__ mscf,
                                               short* __restrict__ mout, int nmask) {
  __shared__ __align__(16) short As[2][64][128];   // 32 KiB
  __shared__ __align__(16) short Bs[2][64][128];   // 32 KiB
  if (blockIdx.x >= 144) {
    const int r = (int)blockIdx.x - 144;
    if (r < nmask) maskmul8(mkf, mmf, mscf[0], mout, r * 256 + (int)threadIdx.x);
    else xcvt_body(x, xbp, (xoff + r - nmask) * 256 + (int)threadIdx.x);
    return;
  }
  const int ntiles = N >> 6;
  const int m0 = (blockIdx.x / ntiles) << 6, n0 = (blockIdx.x % ntiles) << 6;
  const int tid = threadIdx.x;
  const int lane = tid & 63, wv = tid >> 6;
  const int wr = (wv >> 1) * 32, wc = (wv & 1) * 32;
  const int lr = lane & 15, lh = lane >> 4;

  const int rr = tid >> 4, sl = tid & 15;
  const int swz = sl ^ (rr & 7);
  const unsigned aOff = (unsigned)(m0 + rr) * K + swz * 8;
  const unsigned bOff = (unsigned)(n0 + rr) * K + swz * 8;
  const int ldsRow = 4 * wv;

  f32x4 acc[2][2] = {};

#define GST(buf_, kt_) do { \
    _Pragma("unroll") for (int j = 0; j < 4; ++j) \
      g2l16(A + aOff + (unsigned)j * 16u * (unsigned)K + (unsigned)(kt_) * 128u, \
            &As[buf_][j * 16 + ldsRow][0]); \
    _Pragma("unroll") for (int j = 0; j < 4; ++j) \
      g2l16(BT + bOff + (unsigned)j * 16u * (unsigned)K + (unsigned)(kt_) * 128u, \
            &Bs[buf_][j * 16 + ldsRow][0]); \
  } while (0)

  const int nk = K >> 7;
  GST(0, 0);
  asm volatile("s_waitcnt vmcnt(0)" ::: "memory");
  __builtin_amdgcn_s_barrier();

  for (int kt = 0; kt < nk; ++kt) {
    const int cur = kt & 1;
    if (kt + 1 < nk) { if (cur) GST(0, kt + 1); else GST(1, kt + 1); }
#pragma unroll
    for (int ks = 0; ks < 4; ++ks) {
      short8 af[2], bf[2];
#pragma unroll
      for (int i = 0; i < 2; ++i)
        af[i] = *(const short8*)&As[cur][wr + i * 16 + lr][((ks * 4 + lh) ^ (lr & 7)) * 8];
#pragma unroll
      for (int i = 0; i < 2; ++i)
        bf[i] = *(const short8*)&Bs[cur][wc + i * 16 + lr][((ks * 4 + lh) ^ (lr & 7)) * 8];
#pragma unroll
      for (int mi = 0; mi < 2; ++mi)
#pragma unroll
        for (int ni = 0; ni < 2; ++ni)
          acc[mi][ni] = MF(af[mi], bf[ni], acc[mi][ni]);
    }
    if (kt + 1 < nk) asm volatile("s_waitcnt vmcnt(0)" ::: "memory");
    __builtin_amdgcn_s_barrier();
  }
#pragma unroll
  for (int mi = 0; mi < 2; ++mi) {
    const int row = m0 + wr + mi * 16 + lh * 4;
#pragma unroll
    for (int ni = 0; ni < 2; ++ni) {
      const int col = n0 + wc + ni * 16 + lr;
#pragma unroll
      for (int q = 0; q < 4; ++q)
        C[(size_t)(row + q) * N + col] = f2bf(acc[mi][ni][q]);
    }
  }
#undef GST
}

// ======== conv: 256x128 tile, 4 waves x (128x64), single-buffer BK=64, 1 barrier/phase ========
// (R10/R16-proven structure, plain stores)
#define RD_A(mf_, ks_) \
  (*(const short8*)&As[wr * 128 + (mf_) * 16 + lr][(((ks_) * 4 + lh) ^ (lr & 7)) * 8])
#define RD_B(nf_, ks_) \
  (*(const short8*)&Bs[wc * 64 + (nf_) * 16 + lr][(((ks_) * 4 + lh) ^ (lr & 7)) * 8])

#define STAGE_AQ(q_, tt_) do { \
  const int tc_ = (tt_) > 17 ? 17 : (tt_); \
  const int khw_ = tc_ >> 1; const int kh_ = (khw_ * 11) >> 5; const int kw_ = khw_ - kh_ * 3; \
  const int ao_ = (kh_ * 34 + kw_) * 128 + ((tc_ & 1) << 6) + (q_) * 4352; \
  g2l16(xbp + aBase + ao_, &As[(q_) * 32 + ldsA][0]); \
  g2l16(xbp + aBase + 17408 + ao_, &As[128 + (q_) * 32 + ldsA][0]); } while (0)

#define STAGE_B(tt_) do { \
  const int tc_ = (tt_) > 17 ? 17 : (tt_); \
  g2l16(wT + bBase +          tc_ * 64, &Bs[     ldsA][0]); \
  g2l16(wT + bBase +  36864 + tc_ * 64, &Bs[32 + ldsA][0]); \
  g2l16(wT + bBase +  73728 + tc_ * 64, &Bs[64 + ldsA][0]); \
  g2l16(wT + bBase + 110592 + tc_ * 64, &Bs[96 + ldsA][0]); } while (0)

#define MFMA16(p_) \
  acc[2*(p_)  ][0] = MF(a0k0, bfr[0][0], acc[2*(p_)  ][0]); \
  acc[2*(p_)  ][1] = MF(a0k0, bfr[1][0], acc[2*(p_)  ][1]); \
  acc[2*(p_)  ][2] = MF(a0k0, bfr[2][0], acc[2*(p_)  ][2]); \
  acc[2*(p_)  ][3] = MF(a0k0, bfr[3][0], acc[2*(p_)  ][3]); \
  acc[2*(p_)+1][0] = MF(a1k0, bfr[0][0], acc[2*(p_)+1][0]); \
  acc[2*(p_)+1][1] = MF(a1k0, bfr[1][0], acc[2*(p_)+1][1]); \
  acc[2*(p_)+1][2] = MF(a1k0, bfr[2][0], acc[2*(p_)+1][2]); \
  acc[2*(p_)+1][3] = MF(a1k0, bfr[3][0], acc[2*(p_)+1][3]); \
  acc[2*(p_)  ][0] = MF(a0k1, bfr[0][1], acc[2*(p_)  ][0]); \
  acc[2*(p_)  ][1] = MF(a0k1, bfr[1][1], acc[2*(p_)  ][1]); \
  acc[2*(p_)  ][2] = MF(a0k1, bfr[2][1], acc[2*(p_)  ][2]); \
  acc[2*(p_)  ][3] = MF(a0k1, bfr[3][1], acc[2*(p_)  ][3]); \
  acc[2*(p_)+1][0] = MF(a1k1, bfr[0][1], acc[2*(p_)+1][0]); \
  acc[2*(p_)+1][1] = MF(a1k1, bfr[1][1], acc[2*(p_)+1][1]); \
  acc[2*(p_)+1][2] = MF(a1k1, bfr[2][1], acc[2*(p_)+1][2]); \
  acc[2*(p_)+1][3] = MF(a1k1, bfr[3][1], acc[2*(p_)+1][3]);

#define PHASE(p_, PRE, WAITV, ...) do { \
  PRE; \
  short8 a0k0 = RD_A(2*(p_), 0),   a0k1 = RD_A(2*(p_), 1); \
  short8 a1k0 = RD_A(2*(p_)+1, 0), a1k1 = RD_A(2*(p_)+1, 1); \
  __VA_ARGS__ \
  asm volatile("s_waitcnt lgkmcnt(0)" ::: "memory"); \
  __builtin_amdgcn_sched_barrier(0); \
  __builtin_amdgcn_s_setprio(1); \
  MFMA16(p_) \
  __builtin_amdgcn_s_setprio(0); \
  WAITV; \
  __builtin_amdgcn_s_barrier(); \
} while (0)

#define LOADB do { \
  bfr[0][0] = RD_B(0, 0); bfr[0][1] = RD_B(0, 1); \
  bfr[1][0] = RD_B(1, 0); bfr[1][1] = RD_B(1, 1); \
  bfr[2][0] = RD_B(2, 0); bfr[2][1] = RD_B(2, 1); \
  bfr[3][0] = RD_B(3, 0); bfr[3][1] = RD_B(3, 1); } while (0)

#define VM4 asm volatile("s_waitcnt vmcnt(4)" ::: "memory")
#define VM6 asm volatile("s_waitcnt vmcnt(6)" ::: "memory")
#define VM8 asm volatile("s_waitcnt vmcnt(8)" ::: "memory")

__global__ __launch_bounds__(256, 2) void k_conv(const short* __restrict__ xbp,
                                                 const short* __restrict__ wT,
                                                 const float* __restrict__ bias,
                                                 float* __restrict__ outp) {
  __shared__ __align__(16) short As[256][64];   // 32 KiB
  __shared__ __align__(16) short Bs[128][64];   // 16 KiB
  int bid = blockIdx.x;
  bid = (bid & 7) * 64 + (bid >> 3);            // bijective XCD swizzle (512 % 8 == 0)
  const int mt = bid >> 2, nt = bid & 3;
  const int m0 = mt << 8, n0 = nt << 7;
  const int tid = threadIdx.x;
  const int lane = tid & 63, wid = tid >> 6;    // 4 waves: 2M x 2N
  const int wr = wid >> 1, wc = wid & 1;
  const int lr = lane & 15, lh = lane >> 4;

  f32x4 acc[8][4] = {};
  short8 bfr[4][2];

  const int rsub = tid >> 3;                    // 0..31
  const int sw = (tid & 7) ^ (rsub & 7);        // pre-swizzled 16B slot
  const int ldsA = wid * 8;                     // wave-uniform LDS row base

  const int Mb = m0 + rsub;
  const int b = Mb >> 10, h0 = (Mb >> 5) & 31, w = Mb & 31;
  const unsigned aBase = (unsigned)((b * 34 + h0) * 34 + w) * 128 + sw * 8;
  const unsigned bBase = (unsigned)(n0 + rsub) * 1152 + sw * 8;

  STAGE_B(0);
  STAGE_AQ(0, 0); STAGE_AQ(1, 0); STAGE_AQ(2, 0);
  asm volatile("s_waitcnt vmcnt(0)" ::: "memory");
  __builtin_amdgcn_s_barrier();

  for (int t = 0; t < 18; ++t) {
    const int tn = t + 1;  // clamped inside STAGE macros (idempotent restage at tail)
    PHASE(0, LOADB, VM4, STAGE_AQ(3, t););
    PHASE(1, ,      VM6, STAGE_B(tn););
    PHASE(2, ,      VM8, STAGE_AQ(0, tn); STAGE_AQ(1, tn););
    PHASE(3, ,      VM4, STAGE_AQ(2, tn););
  }
  asm volatile("s_waitcnt vmcnt(0)" ::: "memory");

  // epilogue: fp32 + bias
  const int orow = m0 + wr * 128, ocol = n0 + wc * 64;
#pragma unroll
  for (int mf = 0; mf < 8; ++mf) {
    const int row = orow + mf * 16 + lh * 4;
#pragma unroll
    for (int nf = 0; nf < 4; ++nf) {
      const int col = ocol + nf * 16 + lr;
      const float bv = bias[col];
#pragma unroll
      for (int q = 0; q < 4; ++q)
        outp[(size_t)(row + q) * 512 + col] = acc[mf][nf][q] + bv;
    }
  }
}

extern "C" void kernel_launch(void* const* d_in, const int* in_sizes, int n_in,
                              void* d_out, int out_size, void* d_ws, size_t ws_size,
                              hipStream_t stream) {
  (void)in_sizes; (void)n_in; (void)out_size; (void)ws_size;
  const float* x    = (const float*)d_in[0];
  const float* k0   = (const float*)d_in[1];
  const float* k1   = (const float*)d_in[2];
  const float* k2   = (const float*)d_in[3];
  const float* m0   = (const float*)d_in[4];
  const float* m1   = (const float*)d_in[5];
  const float* m2   = (const float*)d_in[6];
  const float* sc   = (const float*)d_in[7];
  const float* bias = (const float*)d_in[8];
  float* outp = (float*)d_out;
  char* ws = (char*)d_ws;

  short* xbp = (short*)(ws);              // 32*34*34*128 bf16 = 9,469,952 B
  short* w1b = (short*)(ws + 9469952);    // 1152*1152 bf16    = 2,654,208 B
  short* w2b = (short*)(ws + 12124160);   // 1152*512 bf16     = 1,179,648 B (plain)
  short* w3T = (short*)(ws + 13303808);   // 512*512 bf16      =   524,288 B
  short* B1T = (short*)(ws + 13828096);   // 512*1152 bf16     = 1,179,648 B
  short* wET = (short*)(ws + 15007744);   // 512*1152 bf16     = 1,179,648 B

  // pipeline: prep1{w2b,w3T,xcvt[0..1023]} -> gemmB1 || w1b-maskmul || xcvt[1024..1535]
  //           -> gemmEff || xcvt[1536..2311] -> conv
  k_prep1<<<1568, 256, 0, stream>>>(k1, m1, k2, m2, w2b, w3T, x, xbp);
  // B1T[512][1152] = w3T[512][512] @ w2b[1152][512]^T  (K=512, 4 BK-stages)
  k_gemmx<<<1304, 256, 0, stream>>>(w3T, w2b, B1T, 512, 1152, 512,
                                    x, xbp, 1024, k0, m0, sc, w1b, 648);
  // wET[512][1152] = B1T[512][1152] @ w1b[1152][1152]^T  (K=1152, 9 BK-stages)
  k_gemmx<<<920, 256, 0, stream>>>(B1T, w1b, wET, 512, 1152, 1152,
                                   x, xbp, 1536, (const float*)nullptr,
                                   (const float*)nullptr, (const float*)nullptr,
                                   (short*)nullptr, 0);
  k_conv<<<512, 256, 0, stream>>>(xbp, wET, bias, outp);
}